// Round 16
// baseline (95.954 us; speedup 1.0000x reference)
//
#include <hip/hip_runtime.h>
#include <math.h>

#define BATCH_  256
#define NTOT    16384
#define ETOT    524288

typedef __attribute__((ext_vector_type(8))) short short8v;
typedef __attribute__((ext_vector_type(4))) float f32x4;

#define MFMA16(a,b,c) __builtin_amdgcn_mfma_f32_16x16x32_bf16((a),(b),(c),0,0,0)

__device__ __forceinline__ unsigned short f2bf(float f) {
    unsigned int x = __float_as_uint(f);
    return (unsigned short)((x + 0x7fffu + ((x >> 16) & 1u)) >> 16);
}
__device__ __forceinline__ float bf2f(unsigned short h) {
    return __uint_as_float(((unsigned int)h) << 16);
}
__device__ __forceinline__ float softplus_f(float v) {
    return v > 20.f ? v : log1pf(expf(v));
}
__device__ __forceinline__ float dot4(f32x4 a, f32x4 b) {
    float z = a[0] * b[0];
    z = fmaf(a[1], b[1], z);
    z = fmaf(a[2], b[2], z);
    z = fmaf(a[3], b[3], z);
    return z;
}
__device__ __forceinline__ void packfrag(f32x4 a, f32x4 q, short8v& hi, short8v& lo) {
    float v[8] = {a[0], a[1], a[2], a[3], q[0], q[1], q[2], q[3]};
#pragma unroll
    for (int j = 0; j < 8; j++) {
        const unsigned short h = f2bf(v[j]);
        hi[j] = (short)h;
        lo[j] = (short)f2bf(v[j] - bf2f(h));
    }
}
// hi-only pack via HW packed converter (RNE), 4 VALU for 8 values
__device__ __forceinline__ short8v cvthi8(f32x4 a, f32x4 q) {
    union { short8v s; unsigned int u[4]; } r;
    asm("v_cvt_pk_bf16_f32 %0, %1, %2" : "=v"(r.u[0]) : "v"(a[0]), "v"(a[1]));
    asm("v_cvt_pk_bf16_f32 %0, %1, %2" : "=v"(r.u[1]) : "v"(a[2]), "v"(a[3]));
    asm("v_cvt_pk_bf16_f32 %0, %1, %2" : "=v"(r.u[2]) : "v"(q[0]), "v"(q[1]));
    asm("v_cvt_pk_bf16_f32 %0, %1, %2" : "=v"(r.u[3]) : "v"(q[2]), "v"(q[3]));
    return r.s;
}

// ---------------------------------------------------------------------------
// K0: pre-pack split-bf16 (hi/lo) MFMA A-fragments of W1 (160x256, kt 0..4)
// and W2 (256x256, kt 0..7). Unit u = kt*16 + cht (W1: u 0..79; W2: u 80..207):
// frags[u*1024 + hl*512 + l*8 + j] = W[(kt*32+(l>>4)*8+j)*256 + cht*16+(l&15)]
// ---------------------------------------------------------------------------
__global__ __launch_bounds__(256) void k_prep(const float* __restrict__ W1,
                                              const float* __restrict__ W2,
                                              unsigned short* __restrict__ frags) {
    const int u = blockIdx.x;
    const float* S = (u < 80) ? W1 : W2;
    const int ul = (u < 80) ? u : (u - 80);
    const int rowbase = (ul >> 4) * 32;
    const int cht = ul & 15;
    for (int idx = threadIdx.x; idx < 512; idx += 256) {
        const int l = idx >> 3, j = idx & 7;
        const int row = rowbase + ((l >> 4) << 3) + j;
        const int col = cht * 16 + (l & 15);
        const float v = S[row * 256 + col];
        const unsigned short h = f2bf(v);
        frags[u * 1024 + idx]       = h;
        frags[u * 1024 + 512 + idx] = f2bf(v - bf2f(h));
    }
}

// ---------------------------------------------------------------------------
// K1: phases A+B per (batch, channel-quarter). Grid 1024 (b = bx&255,
// q = bx>>8). 512 thr, 8 waves (ng = w&3, sq = w>>2); wave = 16 nodes x
// 2 chts. waves_per_eu(2) (only no-spill >64-VGPR point on this toolchain).
// NO eaf prep pass this round: ea read DIRECTLY as f32 with a depth-4
// register landing pipeline (Fa/Fb[4], convert to bf16 at use via v_cvt_pk).
// Coalescing: 4 lanes x 32B = 128B contiguous per node-row, 16 rows/wave
// (full 64B-line utilization); quarters q>=1 re-read L2/L3-hot ea.
// Analytic dst d = (node+1+o)&63 (validated round 15). Barrier-free phase B,
// ONE block barrier total. LDS: s_xwb[64][64] f32 swizzled = 16 KB.
// ---------------------------------------------------------------------------
__global__ __launch_bounds__(512) __attribute__((amdgpu_waves_per_eu(2)))
void k_ab6(
    const float* __restrict__ x, const float* __restrict__ ea,
    const float* __restrict__ b1, const unsigned short* __restrict__ frags,
    float* __restrict__ sumh1)
{
    __shared__ __align__(16) float s_xwb[64 * 64];   // 16 KB, swizzled

    const int b = blockIdx.x & 255, q = blockIdx.x >> 8;
    const int tid = threadIdx.x;
    const int l = tid & 63, w = tid >> 6, g = l >> 4, l15 = l & 15;
    const int ng = w & 3, sq = w >> 2;           // sq in {0,1}
    const int node = ng * 16 + l15;
    const int swzn = (l15 & 7) << 2;

    // ea row pointer for this lane: 8 floats at k = g*8 of each offset-row
    const float* earow = ea + ((size_t)(b * 64 + node)) * 1024 + g * 8;

    // depth-4 landing pipeline: issue offsets 0..3 before phase A (overlap)
    f32x4 Fa[4], Fb[4];
#pragma unroll
    for (int i = 0; i < 4; i++) {
        Fa[i] = *(const f32x4*)(earow + (size_t)i * 32);
        Fb[i] = *(const f32x4*)(earow + (size_t)i * 32 + 4);
    }

    // ================= phase A =================
    short8v Xh[2], Xl[2];
#pragma unroll
    for (int kt = 0; kt < 2; kt++) {
        const float* p = x + (size_t)(b * 64 + node) * 64 + kt * 32 + g * 8;
        packfrag(*(const f32x4*)p, *(const f32x4*)(p + 4), Xh[kt], Xl[kt]);
    }

    f32x4 xab1[2];
#pragma unroll
    for (int i = 0; i < 2; i++) {
        const int cht = q * 4 + sq * 2 + i;
        f32x4 d = *(const f32x4*)&b1[cht * 16 + g * 4];   // C-init = b1
#pragma unroll
        for (int kt = 0; kt < 2; kt++) {
            const int base = (kt * 16 + cht) * 1024 + l * 8;
            const short8v Ahh = *(const short8v*)&frags[base];
            const short8v All = *(const short8v*)&frags[base + 512];
            d = MFMA16(All, Xh[kt], d);
            d = MFMA16(Ahh, Xl[kt], d);
            d = MFMA16(Ahh, Xh[kt], d);
        }
        xab1[i] = d;
    }

#pragma unroll
    for (int i = 0; i < 2; i++) {
        const int cht = q * 4 + sq * 2 + i;
        f32x4 d = {0.f, 0.f, 0.f, 0.f};
#pragma unroll
        for (int kt = 0; kt < 2; kt++) {
            const int base = ((kt + 2) * 16 + cht) * 1024 + l * 8;
            const short8v Ahh = *(const short8v*)&frags[base];
            const short8v All = *(const short8v*)&frags[base + 512];
            d = MFMA16(All, Xh[kt], d);
            d = MFMA16(Ahh, Xl[kt], d);
            d = MFMA16(Ahh, Xh[kt], d);
        }
        const int lc = (sq * 2 + i) * 16 + g * 4;   // local col in quarter
        *(f32x4*)&s_xwb[node * 64 + (lc ^ swzn)] = d;
    }

    // W1c A-frags (units 64..79), register-cached
    short8v Ah[2], Al[2];
#pragma unroll
    for (int i = 0; i < 2; i++) {
        const int base = (64 + q * 4 + sq * 2 + i) * 1024 + l * 8;
        Ah[i] = *(const short8v*)&frags[base];
        Al[i] = *(const short8v*)&frags[base + 512];
    }

    __syncthreads();   // xwb visible — the ONLY block barrier

    // ================= phase B ================= (barrier-free, 32 offsets)
    f32x4 acc[2];
#pragma unroll
    for (int i = 0; i < 2; i++) acc[i] = (f32x4){0.f, 0.f, 0.f, 0.f};

    for (int c = 0; c < 8; ++c) {
#pragma unroll
        for (int o4 = 0; o4 < 4; o4++) {
            const int o = c * 4 + o4;
            // convert landed f32 (load issued 4 iterations ago) to bf16
            const short8v Bh = cvthi8(Fa[o4], Fb[o4]);
            // refill this slot for offset o+4 (issue before compute)
            if (o < 28) {
                Fa[o4] = *(const f32x4*)(earow + (size_t)(o + 4) * 32);
                Fb[o4] = *(const f32x4*)(earow + (size_t)(o + 4) * 32 + 4);
            }

            const int d = (node + 1 + o) & 63;     // analytic dst
            const int swzd = (d & 7) << 2;

#pragma unroll
            for (int i = 0; i < 2; i++) {
                const int lcb = (sq * 2 + i) * 16 + g * 4;
                const f32x4 wb = *(const f32x4*)&s_xwb[d * 64 + (lcb ^ swzd)];
                f32x4 di = MFMA16(Al[i], Bh, xab1[i]);   // 2-term split
                di = MFMA16(Ah[i], Bh, di);
#pragma unroll
                for (int r = 0; r < 4; r++)
                    acc[i][r] += fmaxf(di[r] + wb[r], 0.f);
            }
        }
    }

    // write sumh1 (global, linear [node][256])
    const size_t grow = (size_t)b * 64 + node;
#pragma unroll
    for (int i = 0; i < 2; i++) {
        const int cg = (q * 4 + sq * 2 + i) * 16 + g * 4;
        *(f32x4*)&sumh1[grow * 256 + cg] = acc[i];
    }
}

// ---------------------------------------------------------------------------
// K2: phases C+D per batch. 256 blocks, 1024 thr (16 waves).
// Stage sumh1 -> LDS swizzled; C: agg = sumh1@W2 + 32*b2 (16-wave split);
// stage head weights -> LDS; D: factored u/v dots; heads -> out.
// ---------------------------------------------------------------------------
__global__ __launch_bounds__(1024) __attribute__((amdgpu_waves_per_eu(2)))
void k_cd2(
    const float* __restrict__ x, const float* __restrict__ sumh1,
    const int* __restrict__ edges, const float* __restrict__ high,
    const unsigned short* __restrict__ frags, const float* __restrict__ b2,
    const float* __restrict__ Wmu,  const float* __restrict__ bmu,
    const float* __restrict__ Wsig, const float* __restrict__ bsig,
    const float* __restrict__ Wmu2, const float* __restrict__ bmu2,
    const float* __restrict__ Wsig2,const float* __restrict__ bsig2,
    float* __restrict__ out)
{
    __shared__ __align__(16) unsigned char smem[131072];
    float* s_sumh1 = (float*)smem;             // [64][256] swizzled
    float* s_agg   = (float*)(smem + 65536);   // [64][256] swizzled
    float* s_su    = (float*)smem;             // [64][4]   (after C)
    float* s_su2   = (float*)(smem + 1024);    // [8][2]
    float* s_w     = (float*)(smem + 2048);    // [1920] head weights

    const int b = blockIdx.x, tid = threadIdx.x;
    const int l = tid & 63, w = tid >> 6, g = l >> 4, l15 = l & 15;
    const int swzn = (l15 & 7) << 2;

    // ---- stage sumh1 (coalesced) into swizzled LDS
    for (int idx = tid; idx < 4096; idx += 1024) {
        const int row = idx >> 6, c4 = (idx & 63) * 4;
        const f32x4 v = *(const f32x4*)&sumh1[(size_t)b * 16384 + (size_t)idx * 4];
        *(f32x4*)&s_sumh1[row * 256 + (c4 ^ ((row & 7) << 2))] = v;
    }
    __syncthreads();

    // ================= phase C =================  wave = (rt = w&3, cj = w>>2)
    const int rt = w & 3, cj = w >> 2;   // 4 row-tiles x 4 col-groups(4 chts)
    f32x4 acc2[4];
#pragma unroll
    for (int j = 0; j < 4; j++) acc2[j] = (f32x4){0.f, 0.f, 0.f, 0.f};

    for (int ks = 0; ks < 8; ks++) {
        const int row = rt * 16 + l15;
        const int cbk = ks * 32 + g * 8;
        const f32x4 a0 = *(const f32x4*)&s_sumh1[row * 256 + (cbk ^ swzn)];
        const f32x4 a1 = *(const f32x4*)&s_sumh1[row * 256 + ((cbk + 4) ^ swzn)];
        short8v Ahh, All;
        packfrag(a0, a1, Ahh, All);
#pragma unroll
        for (int j = 0; j < 4; j++) {
            const int base = (80 + ks * 16 + cj * 4 + j) * 1024 + l * 8;
            const short8v Bh = *(const short8v*)&frags[base];
            const short8v Bl = *(const short8v*)&frags[base + 512];
            acc2[j] = MFMA16(Ahh, Bh, acc2[j]);
            acc2[j] = MFMA16(Ahh, Bl, acc2[j]);
            acc2[j] = MFMA16(All, Bh, acc2[j]);
        }
    }

#pragma unroll
    for (int j = 0; j < 4; j++) {
        const int col = (cj * 4 + j) * 16 + l15;
        const float bb = 32.f * b2[col];
#pragma unroll
        for (int r = 0; r < 4; r++) {
            const int row = rt * 16 + g * 4 + r;
            s_agg[row * 256 + (col ^ ((row & 7) << 2))] = acc2[j][r] + bb;
        }
    }
    __syncthreads();   // all sumh1 reads done -> region reusable

    // ---- stage head weights into LDS (broadcast-read in D)
    for (int i = tid; i < 1920; i += 1024)
        s_w[i] = (i < 640) ? Wmu[i]
               : (i < 1280) ? Wsig[i - 640]
               : (i < 1600) ? Wmu2[i - 1280] : Wsig2[i - 1600];
    __syncthreads();

    // ================= phase D =================
    if (tid < 256) {
        const int n = tid >> 2, s = tid & 3;
        const float* Wp = s_w + (s & 1) * 640 + ((s >> 1) ? 320 : 0);
        const float* xr = x + (size_t)(b * 64 + n) * 64;
        const int sw = (n & 7) << 2;
        float z = 0.f;
#pragma unroll
        for (int kq = 0; kq < 16; kq++)
            z += dot4(*(const f32x4*)&xr[kq * 4], *(const f32x4*)&Wp[kq * 4]);
#pragma unroll 8
        for (int kq = 0; kq < 64; kq++)
            z += dot4(*(const f32x4*)&s_agg[n * 256 + ((kq * 4) ^ sw)],
                      *(const f32x4*)&Wp[64 + kq * 4]);
        s_su[n * 4 + s] = z;
    } else if (tid < 272) {
        const int j = (tid - 256) >> 1, s = tid & 1;
        const int n = 56 + j;
        const float* Wp = s_w + 1280 + (s ? 320 : 0);
        const float* xr = x + (size_t)(b * 64 + n) * 64;
        const int sw = (n & 7) << 2;
        float z = 0.f;
#pragma unroll
        for (int kq = 0; kq < 16; kq++)
            z += dot4(*(const f32x4*)&xr[kq * 4], *(const f32x4*)&Wp[kq * 4]);
#pragma unroll 8
        for (int kq = 0; kq < 64; kq++)
            z += dot4(*(const f32x4*)&s_agg[n * 256 + ((kq * 4) ^ sw)],
                      *(const f32x4*)&Wp[64 + kq * 4]);
        s_su2[j * 2 + s] = z;
    }
    __syncthreads();

    if (tid < 128) {
        const int e0 = edges[tid * 2], e1 = edges[tid * 2 + 1];
        const float a  = softplus_f(s_su[e0 * 4 + 0] + s_su[e1 * 4 + 2] + bmu[0])  + 1e-20f;
        const float be = softplus_f(s_su[e0 * 4 + 1] + s_su[e1 * 4 + 3] + bsig[0]) + 1e-20f;
        out[(size_t)b * 136 + tid] = a / (a + be) * high[tid];
    } else if (tid < 136) {
        const int j = tid - 128;
        const float a  = softplus_f(s_su2[j * 2 + 0] + bmu2[0])  + 1e-20f;
        const float be = softplus_f(s_su2[j * 2 + 1] + bsig2[0]) + 1e-20f;
        out[(size_t)b * 136 + tid] = a / (a + be) * high[128 + j];
    }
}

// ---------------------------------------------------------------------------
extern "C" void kernel_launch(void* const* d_in, const int* in_sizes, int n_in,
                              void* d_out, int out_size, void* d_ws, size_t ws_size,
                              hipStream_t stream) {
    const float* x     = (const float*)d_in[0];
    const float* ea    = (const float*)d_in[2];
    const int*   edges = (const int*)  d_in[3];
    const float* high  = (const float*)d_in[4];
    const float* W1    = (const float*)d_in[5];
    const float* b1    = (const float*)d_in[6];
    const float* W2    = (const float*)d_in[7];
    const float* b2    = (const float*)d_in[8];
    const float* Wmu   = (const float*)d_in[9];
    const float* bmu   = (const float*)d_in[10];
    const float* Wsig  = (const float*)d_in[11];
    const float* bsig  = (const float*)d_in[12];
    const float* Wmu2  = (const float*)d_in[13];
    const float* bmu2  = (const float*)d_in[14];
    const float* Wsig2 = (const float*)d_in[15];
    const float* bsig2 = (const float*)d_in[16];
    float* out = (float*)d_out;

    // ws: sumh1 (16384*256 f32 = 16.8 MB) at base | frags (416 KB) at tail
    float* sumh1 = (float*)d_ws;
    const size_t frag_off = (ws_size - (size_t)208 * 2048) & ~(size_t)1023;
    unsigned short* frags = (unsigned short*)((char*)d_ws + frag_off);

    hipLaunchKernelGGL(k_prep, dim3(208),    dim3(256),  0, stream, W1, W2, frags);
    hipLaunchKernelGGL(k_ab6,  dim3(1024),   dim3(512),  0, stream,
                       x, ea, b1, frags, sumh1);
    hipLaunchKernelGGL(k_cd2,  dim3(BATCH_), dim3(1024), 0, stream,
                       x, sumh1, edges, high, frags, b2,
                       Wmu, bmu, Wsig, bsig, Wmu2, bmu2, Wsig2, bsig2, out);
}

// Round 17
// 65.964 us; speedup vs baseline: 1.4546x; 1.4546x over previous
//
#include <hip/hip_runtime.h>
#include <math.h>

#define BATCH_  256
#define NTOT    16384
#define ETOT    524288

typedef __attribute__((ext_vector_type(8))) short short8v;
typedef __attribute__((ext_vector_type(4))) float f32x4;

#define MFMA16(a,b,c) __builtin_amdgcn_mfma_f32_16x16x32_bf16((a),(b),(c),0,0,0)

__device__ __forceinline__ unsigned short f2bf(float f) {
    unsigned int x = __float_as_uint(f);
    return (unsigned short)((x + 0x7fffu + ((x >> 16) & 1u)) >> 16);
}
__device__ __forceinline__ float bf2f(unsigned short h) {
    return __uint_as_float(((unsigned int)h) << 16);
}
__device__ __forceinline__ float softplus_f(float v) {
    return v > 20.f ? v : log1pf(expf(v));
}
__device__ __forceinline__ float dot4(f32x4 a, f32x4 b) {
    float z = a[0] * b[0];
    z = fmaf(a[1], b[1], z);
    z = fmaf(a[2], b[2], z);
    z = fmaf(a[3], b[3], z);
    return z;
}
__device__ __forceinline__ void packfrag(f32x4 a, f32x4 q, short8v& hi, short8v& lo) {
    float v[8] = {a[0], a[1], a[2], a[3], q[0], q[1], q[2], q[3]};
#pragma unroll
    for (int j = 0; j < 8; j++) {
        const unsigned short h = f2bf(v[j]);
        hi[j] = (short)h;
        lo[j] = (short)f2bf(v[j] - bf2f(h));
    }
}
// hi-only pack via HW packed converter (RNE), 4 VALU for 8 values
__device__ __forceinline__ short8v cvthi8(f32x4 a, f32x4 q) {
    union { short8v s; unsigned int u[4]; } r;
    asm("v_cvt_pk_bf16_f32 %0, %1, %2" : "=v"(r.u[0]) : "v"(a[0]), "v"(a[1]));
    asm("v_cvt_pk_bf16_f32 %0, %1, %2" : "=v"(r.u[1]) : "v"(a[2]), "v"(a[3]));
    asm("v_cvt_pk_bf16_f32 %0, %1, %2" : "=v"(r.u[2]) : "v"(q[0]), "v"(q[1]));
    asm("v_cvt_pk_bf16_f32 %0, %1, %2" : "=v"(r.u[3]) : "v"(q[2]), "v"(q[3]));
    return r.s;
}
// async global->LDS DMA, 16B per lane; LDS dest = wave-uniform base + lane*16
__device__ __forceinline__ void gld_lds16(const float* g, float* l) {
    __builtin_amdgcn_global_load_lds(
        (__attribute__((address_space(1))) const unsigned int*)g,
        (__attribute__((address_space(3))) unsigned int*)l,
        16, 0, 0);
}

// ---------------------------------------------------------------------------
// K0: pre-pack split-bf16 (hi/lo) MFMA A-fragments of W1 (160x256, kt 0..4)
// and W2 (256x256, kt 0..7). Unit u = kt*16 + cht (W1: u 0..79; W2: u 80..207):
// frags[u*1024 + hl*512 + l*8 + j] = W[(kt*32+(l>>4)*8+j)*256 + cht*16+(l&15)]
// ---------------------------------------------------------------------------
__global__ __launch_bounds__(256) void k_prep(const float* __restrict__ W1,
                                              const float* __restrict__ W2,
                                              unsigned short* __restrict__ frags) {
    const int u = blockIdx.x;
    const float* S = (u < 80) ? W1 : W2;
    const int ul = (u < 80) ? u : (u - 80);
    const int rowbase = (ul >> 4) * 32;
    const int cht = ul & 15;
    for (int idx = threadIdx.x; idx < 512; idx += 256) {
        const int l = idx >> 3, j = idx & 7;
        const int row = rowbase + ((l >> 4) << 3) + j;
        const int col = cht * 16 + (l & 15);
        const float v = S[row * 256 + col];
        const unsigned short h = f2bf(v);
        frags[u * 1024 + idx]       = h;
        frags[u * 1024 + 512 + idx] = f2bf(v - bf2f(h));
    }
}

// ---------------------------------------------------------------------------
// K1: phases A+B per (batch, channel-half). Grid 512 (half = blockIdx>>8).
// 512 thr, 8 waves, waves_per_eu(2) (only no-spill >64-VGPR point).
// NEW: ea staged by global_load_lds DMA (no VGPR landing -> compiler cannot
// un-pipeline it). Triple-buffered 3x16KB f32 ring, chunk = 2 offsets.
// Per iter: issue DMA for chunk c+2, compute chunk c, s_waitcnt vmcnt(2)
// (chunk c+1 landed, c+2 stays IN FLIGHT - never drain to 0), raw s_barrier.
// LDS staging is LINEAR (DMA constraint); bank-spread achieved by
// PRE-SWIZZLING the global source address: slot s' holds data t = s'^(n&7).
// Analytic dst d = (node+1+o)&63. LDS total: 32K xwb + 48K ring = 80 KB
// -> exactly 2 blocks/CU.
// ---------------------------------------------------------------------------
__global__ __launch_bounds__(512) __attribute__((amdgpu_waves_per_eu(2)))
void k_ab7(
    const float* __restrict__ x, const float* __restrict__ ea,
    const float* __restrict__ b1, const unsigned short* __restrict__ frags,
    float* __restrict__ sumh1)
{
    __shared__ __align__(16) unsigned char smem[81920];
    float* s_xwb = (float*)smem;             // [64][128] f32, XOR-swizzled
    float* s_ea  = (float*)(smem + 32768);   // 3 x [64 nodes][16 slots][4 f32]

    const int b = blockIdx.x & 255, half = blockIdx.x >> 8;
    const int tid = threadIdx.x;
    const int l = tid & 63, w = tid >> 6, g = l >> 4, l15 = l & 15;
    const int ng = w & 3, cqq = w >> 2;          // cqq in {0,1}
    const int node = ng * 16 + l15;
    const int swzn = (l15 & 7) << 2;

    // ---- DMA staging constants: wave w stages nodes w*8..w*8+7 (2 instrs).
    // linear LDS slot s = i*64 + l -> node n = w*8 + i*4 + (l>>4), slot' = l&15;
    // source data for slot' is t = slot' ^ (n&7)  (pre-swizzled source).
    const int n0 = w * 8 + (l >> 4);         // instr 0 node
    const int n1 = n0 + 4;                   // instr 1 node
    const int t0 = (l & 15) ^ (n0 & 7);
    const int t1 = (l & 15) ^ (n1 & 7);
    const float* g0 = ea + ((size_t)(b * 64 + n0)) * 1024 + (t0 >> 3) * 32 + (t0 & 7) * 4;
    const float* g1 = ea + ((size_t)(b * 64 + n1)) * 1024 + (t1 >> 3) * 32 + (t1 & 7) * 4;
    const int ldsw = w * 512;                // float offset of wave's region

    // prologue: DMA chunk0 -> buf0, chunk1 -> buf1 (4 loads in flight)
    gld_lds16(g0,      s_ea + ldsw);
    gld_lds16(g1,      s_ea + ldsw + 256);
    gld_lds16(g0 + 64, s_ea + 4096 + ldsw);
    gld_lds16(g1 + 64, s_ea + 4096 + ldsw + 256);

    // ================= phase A ================= (overlaps DMA latency)
    short8v Xh[2], Xl[2];
#pragma unroll
    for (int kt = 0; kt < 2; kt++) {
        const float* p = x + (size_t)(b * 64 + node) * 64 + kt * 32 + g * 8;
        packfrag(*(const f32x4*)p, *(const f32x4*)(p + 4), Xh[kt], Xl[kt]);
    }

    f32x4 xab1[4];
#pragma unroll
    for (int i = 0; i < 4; i++) {
        const int cht = half * 8 + cqq * 4 + i;
        f32x4 d = *(const f32x4*)&b1[cht * 16 + g * 4];   // C-init = b1
#pragma unroll
        for (int kt = 0; kt < 2; kt++) {
            const int base = (kt * 16 + cht) * 1024 + l * 8;
            const short8v Ahh = *(const short8v*)&frags[base];
            const short8v All = *(const short8v*)&frags[base + 512];
            d = MFMA16(All, Xh[kt], d);
            d = MFMA16(Ahh, Xl[kt], d);
            d = MFMA16(Ahh, Xh[kt], d);
        }
        xab1[i] = d;
    }

#pragma unroll
    for (int i = 0; i < 4; i++) {
        const int cht = half * 8 + cqq * 4 + i;
        f32x4 d = {0.f, 0.f, 0.f, 0.f};
#pragma unroll
        for (int kt = 0; kt < 2; kt++) {
            const int base = ((kt + 2) * 16 + cht) * 1024 + l * 8;
            const short8v Ahh = *(const short8v*)&frags[base];
            const short8v All = *(const short8v*)&frags[base + 512];
            d = MFMA16(All, Xh[kt], d);
            d = MFMA16(Ahh, Xl[kt], d);
            d = MFMA16(Ahh, Xh[kt], d);
        }
        *(f32x4*)&s_xwb[node * 128 + (((cqq * 4 + i) * 16 + g * 4) ^ swzn)] = d;
    }

    // W1c A-frags (units 64..79), register-cached
    short8v Ah[4], Al[4];
#pragma unroll
    for (int i = 0; i < 4; i++) {
        const int base = (64 + half * 8 + cqq * 4 + i) * 1024 + l * 8;
        Ah[i] = *(const short8v*)&frags[base];
        Al[i] = *(const short8v*)&frags[base + 512];
    }

    // chunk0 landed (vmcnt<=2 leaves only chunk1 in flight); xwb writes done
    asm volatile("s_waitcnt vmcnt(2) lgkmcnt(0)" ::: "memory");
    __builtin_amdgcn_sched_barrier(0);
    __builtin_amdgcn_s_barrier();
    __builtin_amdgcn_sched_barrier(0);

    f32x4 acc[4];
#pragma unroll
    for (int i = 0; i < 4; i++) acc[i] = (f32x4){0.f, 0.f, 0.f, 0.f};

    const int nsw = l15 & 7;                 // node & 7

    // ================= phase B ================= (16 chunks x 2 offsets)
    int bufc = 0, bufs = 2;
#pragma unroll 1
    for (int c = 0; c < 16; ++c) {
        if (c < 14) {   // fire-and-forget DMA for chunk c+2
            gld_lds16(g0 + (size_t)(c + 2) * 64, s_ea + bufs * 4096 + ldsw);
            gld_lds16(g1 + (size_t)(c + 2) * 64, s_ea + bufs * 4096 + ldsw + 256);
        }

        const float* bb = s_ea + bufc * 4096 + node * 64;
#pragma unroll
        for (int oo = 0; oo < 2; oo++) {
            const int ta = ((oo * 8 + g * 2)     ^ nsw) * 4;
            const int tb = ((oo * 8 + g * 2 + 1) ^ nsw) * 4;
            const f32x4 e0 = *(const f32x4*)&bb[ta];
            const f32x4 e1 = *(const f32x4*)&bb[tb];
            const short8v Bh = cvthi8(e0, e1);

            const int o = c * 2 + oo;
            const int d = (node + 1 + o) & 63;     // analytic dst
            const int swzd = (d & 7) << 2;

#pragma unroll
            for (int i = 0; i < 4; i++) {
                const int cbl = (cqq * 4 + i) * 16 + g * 4;
                const f32x4 wb = *(const f32x4*)&s_xwb[d * 128 + (cbl ^ swzd)];
                f32x4 di = MFMA16(Al[i], Bh, xab1[i]);   // 2-term split
                di = MFMA16(Ah[i], Bh, di);
#pragma unroll
                for (int r = 0; r < 4; r++)
                    acc[i][r] += fmaxf(di[r] + wb[r], 0.f);
            }
        }

        // counted drain: chunk c+1 landed; chunk c+2 stays in flight
        if (c < 13)      asm volatile("s_waitcnt vmcnt(2) lgkmcnt(0)" ::: "memory");
        else if (c < 15) asm volatile("s_waitcnt vmcnt(0) lgkmcnt(0)" ::: "memory");
        __builtin_amdgcn_sched_barrier(0);
        if (c < 15) {
            __builtin_amdgcn_s_barrier();
            __builtin_amdgcn_sched_barrier(0);
        }
        bufc = (bufc == 2) ? 0 : bufc + 1;
        bufs = (bufs == 2) ? 0 : bufs + 1;
    }

    // write sumh1 (global, linear [node][256])
    const size_t grow = (size_t)b * 64 + node;
#pragma unroll
    for (int i = 0; i < 4; i++) {
        const int cg = (half * 8 + cqq * 4 + i) * 16 + g * 4;
        *(f32x4*)&sumh1[grow * 256 + cg] = acc[i];
    }
}

// ---------------------------------------------------------------------------
// K2: phases C+D per batch. 256 blocks, 1024 thr (16 waves).
// Stage sumh1 -> LDS swizzled; C: agg = sumh1@W2 + 32*b2 (16-wave split);
// stage head weights -> LDS; D: factored u/v dots; heads -> out.
// ---------------------------------------------------------------------------
__global__ __launch_bounds__(1024) __attribute__((amdgpu_waves_per_eu(2)))
void k_cd2(
    const float* __restrict__ x, const float* __restrict__ sumh1,
    const int* __restrict__ edges, const float* __restrict__ high,
    const unsigned short* __restrict__ frags, const float* __restrict__ b2,
    const float* __restrict__ Wmu,  const float* __restrict__ bmu,
    const float* __restrict__ Wsig, const float* __restrict__ bsig,
    const float* __restrict__ Wmu2, const float* __restrict__ bmu2,
    const float* __restrict__ Wsig2,const float* __restrict__ bsig2,
    float* __restrict__ out)
{
    __shared__ __align__(16) unsigned char smem[131072];
    float* s_sumh1 = (float*)smem;             // [64][256] swizzled
    float* s_agg   = (float*)(smem + 65536);   // [64][256] swizzled
    float* s_su    = (float*)smem;             // [64][4]   (after C)
    float* s_su2   = (float*)(smem + 1024);    // [8][2]
    float* s_w     = (float*)(smem + 2048);    // [1920] head weights

    const int b = blockIdx.x, tid = threadIdx.x;
    const int l = tid & 63, w = tid >> 6, g = l >> 4, l15 = l & 15;
    const int swzn = (l15 & 7) << 2;

    // ---- stage sumh1 (coalesced) into swizzled LDS
    for (int idx = tid; idx < 4096; idx += 1024) {
        const int row = idx >> 6, c4 = (idx & 63) * 4;
        const f32x4 v = *(const f32x4*)&sumh1[(size_t)b * 16384 + (size_t)idx * 4];
        *(f32x4*)&s_sumh1[row * 256 + (c4 ^ ((row & 7) << 2))] = v;
    }
    __syncthreads();

    // ================= phase C =================  wave = (rt = w&3, cj = w>>2)
    const int rt = w & 3, cj = w >> 2;   // 4 row-tiles x 4 col-groups(4 chts)
    f32x4 acc2[4];
#pragma unroll
    for (int j = 0; j < 4; j++) acc2[j] = (f32x4){0.f, 0.f, 0.f, 0.f};

    for (int ks = 0; ks < 8; ks++) {
        const int row = rt * 16 + l15;
        const int cbk = ks * 32 + g * 8;
        const f32x4 a0 = *(const f32x4*)&s_sumh1[row * 256 + (cbk ^ swzn)];
        const f32x4 a1 = *(const f32x4*)&s_sumh1[row * 256 + ((cbk + 4) ^ swzn)];
        short8v Ahh, All;
        packfrag(a0, a1, Ahh, All);
#pragma unroll
        for (int j = 0; j < 4; j++) {
            const int base = (80 + ks * 16 + cj * 4 + j) * 1024 + l * 8;
            const short8v Bh = *(const short8v*)&frags[base];
            const short8v Bl = *(const short8v*)&frags[base + 512];
            acc2[j] = MFMA16(Ahh, Bh, acc2[j]);
            acc2[j] = MFMA16(Ahh, Bl, acc2[j]);
            acc2[j] = MFMA16(All, Bh, acc2[j]);
        }
    }

#pragma unroll
    for (int j = 0; j < 4; j++) {
        const int col = (cj * 4 + j) * 16 + l15;
        const float bb = 32.f * b2[col];
#pragma unroll
        for (int r = 0; r < 4; r++) {
            const int row = rt * 16 + g * 4 + r;
            s_agg[row * 256 + (col ^ ((row & 7) << 2))] = acc2[j][r] + bb;
        }
    }
    __syncthreads();   // all sumh1 reads done -> region reusable

    // ---- stage head weights into LDS (broadcast-read in D)
    for (int i = tid; i < 1920; i += 1024)
        s_w[i] = (i < 640) ? Wmu[i]
               : (i < 1280) ? Wsig[i - 640]
               : (i < 1600) ? Wmu2[i - 1280] : Wsig2[i - 1600];
    __syncthreads();

    // ================= phase D =================
    if (tid < 256) {
        const int n = tid >> 2, s = tid & 3;
        const float* Wp = s_w + (s & 1) * 640 + ((s >> 1) ? 320 : 0);
        const float* xr = x + (size_t)(b * 64 + n) * 64;
        const int sw = (n & 7) << 2;
        float z = 0.f;
#pragma unroll
        for (int kq = 0; kq < 16; kq++)
            z += dot4(*(const f32x4*)&xr[kq * 4], *(const f32x4*)&Wp[kq * 4]);
#pragma unroll 8
        for (int kq = 0; kq < 64; kq++)
            z += dot4(*(const f32x4*)&s_agg[n * 256 + ((kq * 4) ^ sw)],
                      *(const f32x4*)&Wp[64 + kq * 4]);
        s_su[n * 4 + s] = z;
    } else if (tid < 272) {
        const int j = (tid - 256) >> 1, s = tid & 1;
        const int n = 56 + j;
        const float* Wp = s_w + 1280 + (s ? 320 : 0);
        const float* xr = x + (size_t)(b * 64 + n) * 64;
        const int sw = (n & 7) << 2;
        float z = 0.f;
#pragma unroll
        for (int kq = 0; kq < 16; kq++)
            z += dot4(*(const f32x4*)&xr[kq * 4], *(const f32x4*)&Wp[kq * 4]);
#pragma unroll 8
        for (int kq = 0; kq < 64; kq++)
            z += dot4(*(const f32x4*)&s_agg[n * 256 + ((kq * 4) ^ sw)],
                      *(const f32x4*)&Wp[64 + kq * 4]);
        s_su2[j * 2 + s] = z;
    }
    __syncthreads();

    if (tid < 128) {
        const int e0 = edges[tid * 2], e1 = edges[tid * 2 + 1];
        const float a  = softplus_f(s_su[e0 * 4 + 0] + s_su[e1 * 4 + 2] + bmu[0])  + 1e-20f;
        const float be = softplus_f(s_su[e0 * 4 + 1] + s_su[e1 * 4 + 3] + bsig[0]) + 1e-20f;
        out[(size_t)b * 136 + tid] = a / (a + be) * high[tid];
    } else if (tid < 136) {
        const int j = tid - 128;
        const float a  = softplus_f(s_su2[j * 2 + 0] + bmu2[0])  + 1e-20f;
        const float be = softplus_f(s_su2[j * 2 + 1] + bsig2[0]) + 1e-20f;
        out[(size_t)b * 136 + tid] = a / (a + be) * high[128 + j];
    }
}

// ---------------------------------------------------------------------------
extern "C" void kernel_launch(void* const* d_in, const int* in_sizes, int n_in,
                              void* d_out, int out_size, void* d_ws, size_t ws_size,
                              hipStream_t stream) {
    const float* x     = (const float*)d_in[0];
    const float* ea    = (const float*)d_in[2];
    const int*   edges = (const int*)  d_in[3];
    const float* high  = (const float*)d_in[4];
    const float* W1    = (const float*)d_in[5];
    const float* b1    = (const float*)d_in[6];
    const float* W2    = (const float*)d_in[7];
    const float* b2    = (const float*)d_in[8];
    const float* Wmu   = (const float*)d_in[9];
    const float* bmu   = (const float*)d_in[10];
    const float* Wsig  = (const float*)d_in[11];
    const float* bsig  = (const float*)d_in[12];
    const float* Wmu2  = (const float*)d_in[13];
    const float* bmu2  = (const float*)d_in[14];
    const float* Wsig2 = (const float*)d_in[15];
    const float* bsig2 = (const float*)d_in[16];
    float* out = (float*)d_out;

    // ws: sumh1 (16384*256 f32 = 16.8 MB) at base | frags (416 KB) at tail
    float* sumh1 = (float*)d_ws;
    const size_t frag_off = (ws_size - (size_t)208 * 2048) & ~(size_t)1023;
    unsigned short* frags = (unsigned short*)((char*)d_ws + frag_off);

    hipLaunchKernelGGL(k_prep, dim3(208),    dim3(256),  0, stream, W1, W2, frags);
    hipLaunchKernelGGL(k_ab7,  dim3(512),    dim3(512),  0, stream,
                       x, ea, b1, frags, sumh1);
    hipLaunchKernelGGL(k_cd2,  dim3(BATCH_), dim3(1024), 0, stream,
                       x, sumh1, edges, high, frags, b2,
                       Wmu, bmu, Wsig, bsig, Wmu2, bmu2, Wsig2, bsig2, out);
}